// Round 7
// baseline (511.598 us; speedup 1.0000x reference)
//
#include <hip/hip_runtime.h>

#define N_NODES 20000
#define N_EDGES 640000
#define E_TOT   (N_EDGES + N_NODES)   /* 660000: edges + self loops */
#define IN_DIM  128
#define HIDDEN  256
#define OUT_DIM 64
#define LOG2E 1.4426950408889634f
#define NBIN 1024
#define NSHARD 8

typedef __attribute__((ext_vector_type(2))) float f32x2;

__device__ __forceinline__ unsigned short f2bf(float f) {
    union { float f; unsigned int i; } x; x.f = f;
    unsigned int u = x.i;
    return (unsigned short)((u + 0x7fffu + ((u >> 16) & 1u)) >> 16);  // RTNE
}
__device__ __forceinline__ f32x2 up2(unsigned int p) {   // 2 packed bf16 -> 2 fp32
    f32x2 r;
    r.x = __uint_as_float(p << 16);
    r.y = __uint_as_float(p & 0xffff0000u);
    return r;
}
__device__ __forceinline__ unsigned int pk2(float a, float b) {
    return (unsigned int)f2bf(a) | ((unsigned int)f2bf(b) << 16);
}

// ---------------- CSR build + degree sort (4 kernels) ----------------
// cnt8[s][d]: per-shard counters, shard = blockIdx&7 (~XCD-local lines).

__global__ void zero_all_kernel(int* __restrict__ cnt8, int* __restrict__ hcur) {
    int i = blockIdx.x * blockDim.x + threadIdx.x;
    if (i < NSHARD * N_NODES) cnt8[i] = 0;
    if (i < NBIN) hcur[i] = 0;
}

__global__ void count_kernel(const int* __restrict__ edge_dst, int* __restrict__ cnt8) {
    int i = blockIdx.x * blockDim.x + threadIdx.x;
    if (i >= E_TOT) return;
    int shard = blockIdx.x & (NSHARD - 1);
    int d = (i < N_EDGES) ? edge_dst[i] : (i - N_EDGES);   // implicit self-loop tail
    atomicAdd(&cnt8[shard * N_NODES + d], 1);
}

// One block: per-node degree = sum of 8 shard counts; exclusive scan -> indptr;
// rewrite cnt8[s][d] into ABSOLUTE scatter cursors (indptr[d] + shard prefix);
// plus degree histogram (descending bins) and its scan -> hbase.
__global__ __launch_bounds__(1024) void scan_fused_kernel(int* __restrict__ cnt8,
                                                          int* __restrict__ indptr,
                                                          int* __restrict__ hbase) {
    const int T = 1024;
    const int C = (N_NODES + T - 1) / T;   // 20 per thread
    __shared__ int sums[T];
    __shared__ int hist[NBIN];
    int t = threadIdx.x;
    hist[t] = 0;
    __syncthreads();
    int base = t * C;
    int local[C];
    int s = 0;
#pragma unroll
    for (int i = 0; i < C; i++) {
        int idx = base + i;
        int deg = 0;
        if (idx < N_NODES) {
#pragma unroll
            for (int s8 = 0; s8 < NSHARD; s8++) deg += cnt8[s8 * N_NODES + idx];
            int k = (deg > NBIN - 1) ? (NBIN - 1) : deg;
            atomicAdd(&hist[NBIN - 1 - k], 1);   // descending degree bins
        }
        local[i] = s;
        s += deg;
    }
    sums[t] = s;
    __syncthreads();
    for (int off = 1; off < T; off <<= 1) {
        int v = (t >= off) ? sums[t - off] : 0;
        __syncthreads();
        sums[t] += v;
        __syncthreads();
    }
    int prefix = (t == 0) ? 0 : sums[t - 1];
#pragma unroll
    for (int i = 0; i < C; i++) {
        int idx = base + i;
        if (idx < N_NODES) {
            int ip = prefix + local[i];
            indptr[idx] = ip;
            int running = ip;
#pragma unroll
            for (int s8 = 0; s8 < NSHARD; s8++) {   // counts -> absolute cursors
                int c = cnt8[s8 * N_NODES + idx];
                cnt8[s8 * N_NODES + idx] = running;
                running += c;
            }
        }
    }
    if (t == T - 1) indptr[N_NODES] = prefix + s;   // == E_TOT
    __syncthreads();
    // second scan: hist -> hbase (exclusive)
    int hv = hist[t];
    sums[t] = hv;
    __syncthreads();
    for (int off = 1; off < T; off <<= 1) {
        int v = (t >= off) ? sums[t - off] : 0;
        __syncthreads();
        sums[t] += v;
        __syncthreads();
    }
    hbase[t] = sums[t] - hv;
}

// Edge scatter (sharded cursors) and node perm scatter in one grid.
// Shard mapping (blockIdx&7 at 256/block) matches count_kernel exactly.
__global__ void scatter_both_kernel(const int* __restrict__ edge_src,
                                    const int* __restrict__ edge_dst,
                                    const int* __restrict__ indptr,
                                    int* __restrict__ cnt8,
                                    int* __restrict__ ssrc,
                                    const int* __restrict__ hbase,
                                    int* __restrict__ hcur,
                                    int* __restrict__ perm) {
    int i = blockIdx.x * blockDim.x + threadIdx.x;
    if (i < E_TOT) {
        int shard = blockIdx.x & (NSHARD - 1);
        int d, s;
        if (i < N_EDGES) { d = edge_dst[i]; s = edge_src[i]; }
        else             { d = i - N_EDGES; s = d; }
        int pos = atomicAdd(&cnt8[shard * N_NODES + d], 1);   // absolute cursor
        ssrc[pos] = s;
    } else if (i < E_TOT + N_NODES) {
        int nidx = i - E_TOT;
        int d = indptr[nidx + 1] - indptr[nidx];
        int k = (d > NBIN - 1) ? (NBIN - 1) : d;
        int key = NBIN - 1 - k;
        int pos = hbase[key] + atomicAdd(&hcur[key], 1);
        perm[pos] = nidx;
    }
}

// ---------------- fp32 tiled GEMM + bias + optional relu (R3-proven form) ----------------

__global__ __launch_bounds__(256) void gemm_bias_act(const float* __restrict__ A,
                                                     const float* __restrict__ B,
                                                     const float* __restrict__ bias,
                                                     float* __restrict__ C,
                                                     int M, int Nn, int K, int relu) {
    __shared__ float As[16][65];
    __shared__ float Bs[16][65];
    int tid = threadIdx.x;
    int tx = tid & 15, ty = tid >> 4;
    int row0 = blockIdx.x * 64, col0 = blockIdx.y * 64;
    float acc[4][4] = {};
    for (int k0 = 0; k0 < K; k0 += 16) {
        {
            int r_ = tid >> 2;
            int kq = (tid & 3) * 4;
            int gr = row0 + r_;
            float4 a4 = make_float4(0.f, 0.f, 0.f, 0.f);
            if (gr < M) a4 = *(const float4*)&A[(long)gr * K + k0 + kq];
            As[kq + 0][r_] = a4.x; As[kq + 1][r_] = a4.y;
            As[kq + 2][r_] = a4.z; As[kq + 3][r_] = a4.w;
        }
        {
            int kr = tid >> 4;
            int cq = (tid & 15) * 4;
            float4 b4 = *(const float4*)&B[(long)(k0 + kr) * Nn + col0 + cq];
            Bs[kr][cq + 0] = b4.x; Bs[kr][cq + 1] = b4.y;
            Bs[kr][cq + 2] = b4.z; Bs[kr][cq + 3] = b4.w;
        }
        __syncthreads();
#pragma unroll
        for (int kk = 0; kk < 16; kk++) {
            float a[4], b[4];
#pragma unroll
            for (int i = 0; i < 4; i++) a[i] = As[kk][ty * 4 + i];
#pragma unroll
            for (int j = 0; j < 4; j++) b[j] = Bs[kk][tx * 4 + j];
#pragma unroll
            for (int i = 0; i < 4; i++)
#pragma unroll
                for (int j = 0; j < 4; j++) acc[i][j] += a[i] * b[j];
        }
        __syncthreads();
    }
#pragma unroll
    for (int i = 0; i < 4; i++) {
        int gr = row0 + ty * 4 + i;
        if (gr >= M) continue;
#pragma unroll
        for (int j = 0; j < 4; j++) {
            int gc = col0 + tx * 4 + j;
            float v = acc[i][j] + bias[gc];
            if (relu) v = fmaxf(v, 0.f);
            C[(long)gr * Nn + gc] = v;
        }
    }
}

// ---------------- initial normalize: one wave per row, shfl-only ----------------

__global__ __launch_bounds__(256) void normalize0_kernel(const float* __restrict__ h,
                                                         unsigned short* __restrict__ hnb,
                                                         float* __restrict__ r) {
    int wid = threadIdx.x >> 6, lane = threadIdx.x & 63;
    int i = blockIdx.x * 4 + wid;            // grid exact: 5000*4 = 20000
    const float4* h4 = (const float4*)(h + (long)i * HIDDEN);
    float4 v = h4[lane];
    float ss = v.x * v.x + v.y * v.y + v.z * v.z + v.w * v.w;
#pragma unroll
    for (int off = 32; off; off >>= 1) ss += __shfl_xor(ss, off);
    float rr = sqrtf(ss + 1e-12f);
    float ir = 1.f / rr;
    uint2 o;
    o.x = pk2(v.x * ir, v.y * ir);
    o.y = pk2(v.z * ir, v.w * ir);
    ((uint2*)(hnb + (long)i * HIDDEN))[lane] = o;
    if (lane == 0) r[i] = rr;
}

// ---------------- fused AGNN layer ----------------
// ONE node per wave; edge list split across four 16-lane groups (4 streams/wave
// = R4's instr/edge efficiency) at 20000 waves (2x R4 -> latency hiding).
// No-max softmax (cosine logits bounded): partial (z, acc) merge = plain sums,
// two shfl_xor rounds (16, 32). Degree-sorted perm balances blocks.

__global__ __launch_bounds__(256) void agnn_kernel(const unsigned short* __restrict__ hnb,
                                                   const float* __restrict__ rin,
                                                   const int* __restrict__ indptr,
                                                   const int* __restrict__ ssrc,
                                                   const int* __restrict__ perm,
                                                   unsigned short* __restrict__ hnout,
                                                   float* __restrict__ rout,
                                                   float* __restrict__ hout,
                                                   int write_hn) {
    int lane = threadIdx.x & 63;
    int wid  = threadIdx.x >> 6;
    int sub  = lane >> 4;          // which quarter of the edge list (0..3)
    int gl   = lane & 15;          // lane in 16-group
    int node = perm[blockIdx.x * 4 + wid];   // grid exact: 5000*4 = 20000

    const uint4* tab4 = (const uint4*)hnb;   // one uint4 = 8 bf16; row = 32 uint4
    long nb = (long)node * 32 + gl * 2;
    uint4 ha = tab4[nb], hb = tab4[nb + 1];
    f32x2 hd2[8];
    hd2[0] = up2(ha.x) * LOG2E; hd2[1] = up2(ha.y) * LOG2E;
    hd2[2] = up2(ha.z) * LOG2E; hd2[3] = up2(ha.w) * LOG2E;
    hd2[4] = up2(hb.x) * LOG2E; hd2[5] = up2(hb.y) * LOG2E;
    hd2[6] = up2(hb.z) * LOG2E; hd2[7] = up2(hb.w) * LOG2E;

    int beg = indptr[node], end = indptr[node + 1];
    int deg = end - beg;               // >= 1 (self loop)
    int qb  = deg >> 2, rem = deg & 3;
    int cnt = qb + (sub < rem ? 1 : 0);
    int eb  = beg + sub * qb + min(sub, rem);
    int lim = (cnt > 0) ? (eb + cnt - 1) : beg;   // valid clamp target
    int nmax = max(cnt, __shfl_xor(cnt, 16));
    nmax = max(nmax, __shfl_xor(nmax, 32));       // uniform wave loop bound

    f32x2 acc[8];
#pragma unroll
    for (int p = 0; p < 8; p++) acc[p] = (f32x2)0.f;
    float z = 0.f;

    // 3-deep pipeline prologue: rows for e0,e1 in flight; index for e2 in flight
    int s0 = ssrc[(0 < cnt) ? eb : lim];
    int s1 = ssrc[min(eb + 1, lim)];
    long b0 = (long)s0 * 32 + gl * 2;
    uint4 v0a = tab4[b0], v0b = tab4[b0 + 1];
    float r0 = rin[s0];
    long b1 = (long)s1 * 32 + gl * 2;
    uint4 v1a = tab4[b1], v1b = tab4[b1 + 1];
    float r1 = rin[s1];
    int s2 = ssrc[min(eb + 2, lim)];

    for (int i = 0; i < nmax; i++) {
        uint4 ca = v0a, cb = v0b;
        float cr = r0;
        v0a = v1a; v0b = v1b; r0 = r1;
        long b2 = (long)s2 * 32 + gl * 2;
        v1a = tab4[b2]; v1b = tab4[b2 + 1];
        r1 = rin[s2];
        s2 = ssrc[min(eb + i + 3, lim)];

        f32x2 cf[8];
        cf[0] = up2(ca.x); cf[1] = up2(ca.y); cf[2] = up2(ca.z); cf[3] = up2(ca.w);
        cf[4] = up2(cb.x); cf[5] = up2(cb.y); cf[6] = up2(cb.z); cf[7] = up2(cb.w);
        f32x2 da = cf[0] * hd2[0];
        f32x2 db = cf[1] * hd2[1];
        da += cf[2] * hd2[2];  db += cf[3] * hd2[3];
        da += cf[4] * hd2[4];  db += cf[5] * hd2[5];
        da += cf[6] * hd2[6];  db += cf[7] * hd2[7];
        f32x2 d2 = da + db;
        float d = d2.x + d2.y;
        d += __shfl_xor(d, 1);
        d += __shfl_xor(d, 2);
        d += __shfl_xor(d, 4);
        d += __shfl_xor(d, 8);
        float w = (i < cnt) ? exp2f(d) : 0.f;   // mask tail of shorter streams
        z += w;
        float wr = w * cr;
#pragma unroll
        for (int p = 0; p < 8; p++) acc[p] += cf[p] * wr;
    }

    // merge the 4 partial streams (plain sums -- no max state)
    z += __shfl_xor(z, 16);
    z += __shfl_xor(z, 32);
#pragma unroll
    for (int p = 0; p < 8; p++) {
        acc[p].x += __shfl_xor(acc[p].x, 16);
        acc[p].y += __shfl_xor(acc[p].y, 16);
        acc[p].x += __shfl_xor(acc[p].x, 32);
        acc[p].y += __shfl_xor(acc[p].y, 32);
    }

    float inv = 1.f / z;
    f32x2 o[8];
#pragma unroll
    for (int p = 0; p < 8; p++) {
        f32x2 t = acc[p] * inv;
        t.x = fmaxf(t.x, 0.f);
        t.y = fmaxf(t.y, 0.f);
        o[p] = t;
    }

    if (write_hn) {
        float ss = 0.f;
#pragma unroll
        for (int p = 0; p < 8; p++) ss += o[p].x * o[p].x + o[p].y * o[p].y;
        ss += __shfl_xor(ss, 1);
        ss += __shfl_xor(ss, 2);
        ss += __shfl_xor(ss, 4);
        ss += __shfl_xor(ss, 8);     // full row lives in each 16-lane group
        float rr = sqrtf(ss + 1e-12f);
        float ir = 1.f / rr;
        if (sub == 0) {
            uint4 oa, ob;
            oa.x = pk2(o[0].x * ir, o[0].y * ir);
            oa.y = pk2(o[1].x * ir, o[1].y * ir);
            oa.z = pk2(o[2].x * ir, o[2].y * ir);
            oa.w = pk2(o[3].x * ir, o[3].y * ir);
            ob.x = pk2(o[4].x * ir, o[4].y * ir);
            ob.y = pk2(o[5].x * ir, o[5].y * ir);
            ob.z = pk2(o[6].x * ir, o[6].y * ir);
            ob.w = pk2(o[7].x * ir, o[7].y * ir);
            uint4* outt = (uint4*)hnout;
            outt[nb] = oa;
            outt[nb + 1] = ob;
            if (gl == 0) rout[node] = rr;
        }
    } else {
        if (sub == 0) {
            float4* ho = (float4*)(hout + (long)node * HIDDEN + gl * 16);
            ho[0] = make_float4(o[0].x, o[0].y, o[1].x, o[1].y);
            ho[1] = make_float4(o[2].x, o[2].y, o[3].x, o[3].y);
            ho[2] = make_float4(o[4].x, o[4].y, o[5].x, o[5].y);
            ho[3] = make_float4(o[6].x, o[6].y, o[7].x, o[7].y);
        }
    }
}

// ---------------- launch (11 kernels) ----------------

extern "C" void kernel_launch(void* const* d_in, const int* in_sizes, int n_in,
                              void* d_out, int out_size, void* d_ws, size_t ws_size,
                              hipStream_t stream) {
    const float* x  = (const float*)d_in[0];
    const int* esrc = (const int*)d_in[1];
    const int* edst = (const int*)d_in[2];
    const float* W1 = (const float*)d_in[3];
    const float* b1 = (const float*)d_in[4];
    const float* W2 = (const float*)d_in[5];
    const float* b2 = (const float*)d_in[6];
    float* out = (float*)d_out;

    char* ws = (char*)d_ws;
    float*          h0     = (float*)(ws);                          // 20,480,000 B
    unsigned short* hnA    = (unsigned short*)(ws + 20480000);      // 10,240,000 B
    unsigned short* hnB    = (unsigned short*)(ws + 30720000);      // 10,240,000 B
    float*          rA     = (float*)(ws + 40960000);               // 80,000 B
    float*          rB     = (float*)(ws + 41040000);               // 80,000 B
    int*            indptr = (int*)  (ws + 41120000);               // 80,004 B (pad)
    int*            cnt8   = (int*)  (ws + 41200256);               // 640,000 B
    int*            ssrc   = (int*)  (ws + 41840256);               // 2,640,000 B
    int*            perm   = (int*)  (ws + 44480256);               // 80,000 B
    int*            hbase  = (int*)  (ws + 44560256);               // 4,096 B
    int*            hcur   = (int*)  (ws + 44564352);               // 4,096 B

    zero_all_kernel<<<(NSHARD * N_NODES + 255) / 256, 256, 0, stream>>>(cnt8, hcur);
    count_kernel<<<(E_TOT + 255) / 256, 256, 0, stream>>>(edst, cnt8);
    scan_fused_kernel<<<1, 1024, 0, stream>>>(cnt8, indptr, hbase);
    scatter_both_kernel<<<(E_TOT + N_NODES + 255) / 256, 256, 0, stream>>>(
        esrc, edst, indptr, cnt8, ssrc, hbase, hcur, perm);

    dim3 g1((N_NODES + 63) / 64, HIDDEN / 64);
    gemm_bias_act<<<g1, 256, 0, stream>>>(x, W1, b1, h0, N_NODES, HIDDEN, IN_DIM, 1);

    normalize0_kernel<<<N_NODES / 4, 256, 0, stream>>>(h0, hnA, rA);

    int nblk = N_NODES / 4;   // 5000, exact
    // L0: A -> B, L1: B -> A, L2: A -> B, L3: B -> h0 (fp32)
    agnn_kernel<<<nblk, 256, 0, stream>>>(hnA, rA, indptr, ssrc, perm, hnB, rB, h0, 1);
    agnn_kernel<<<nblk, 256, 0, stream>>>(hnB, rB, indptr, ssrc, perm, hnA, rA, h0, 1);
    agnn_kernel<<<nblk, 256, 0, stream>>>(hnA, rA, indptr, ssrc, perm, hnB, rB, h0, 1);
    agnn_kernel<<<nblk, 256, 0, stream>>>(hnB, rB, indptr, ssrc, perm, hnA, rA, h0, 0);

    dim3 g2((N_NODES + 63) / 64, OUT_DIM / 64);
    gemm_bias_act<<<g2, 256, 0, stream>>>(h0, W2, b2, out, N_NODES, OUT_DIM, HIDDEN, 0);
}

// Round 8
// 323.252 us; speedup vs baseline: 1.5827x; 1.5827x over previous
//
#include <hip/hip_runtime.h>

#define N_NODES 20000
#define N_EDGES 640000
#define E_TOT   (N_EDGES + N_NODES)   /* 660000: edges + self loops */
#define IN_DIM  128
#define HIDDEN  256
#define OUT_DIM 64
#define LOG2E 1.4426950408889634f
#define NSHARD 8

typedef __attribute__((ext_vector_type(2))) float f32x2;

__device__ __forceinline__ unsigned short f2bf(float f) {
    union { float f; unsigned int i; } x; x.f = f;
    unsigned int u = x.i;
    return (unsigned short)((u + 0x7fffu + ((u >> 16) & 1u)) >> 16);  // RTNE
}
__device__ __forceinline__ f32x2 up2(unsigned int p) {   // 2 packed bf16 -> 2 fp32
    f32x2 r;
    r.x = __uint_as_float(p << 16);
    r.y = __uint_as_float(p & 0xffff0000u);
    return r;
}
__device__ __forceinline__ unsigned int pk2(float a, float b) {
    return (unsigned int)f2bf(a) | ((unsigned int)f2bf(b) << 16);
}

// ---------------- CSR build (6 kernels, all O(N*8) phases grid-parallel) ----------------
// cnt8[s][d]: per-shard counters, shard = blockIdx&7 (~XCD-local lines).

__global__ void zero_cnt8_kernel(int* __restrict__ cnt8) {
    int i = blockIdx.x * blockDim.x + threadIdx.x;
    if (i < NSHARD * N_NODES) cnt8[i] = 0;
}

__global__ void count_kernel(const int* __restrict__ edge_dst, int* __restrict__ cnt8) {
    int i = blockIdx.x * blockDim.x + threadIdx.x;
    if (i >= E_TOT) return;
    int shard = blockIdx.x & (NSHARD - 1);
    int d = (i < N_EDGES) ? edge_dst[i] : (i - N_EDGES);   // implicit self-loop tail
    atomicAdd(&cnt8[shard * N_NODES + d], 1);
}

// grid-parallel: deg[i] = sum of 8 shard counts
__global__ void sumdeg_kernel(const int* __restrict__ cnt8, int* __restrict__ deg) {
    int i = blockIdx.x * blockDim.x + threadIdx.x;
    if (i >= N_NODES) return;
    int s = 0;
#pragma unroll
    for (int s8 = 0; s8 < NSHARD; s8++) s += cnt8[s8 * N_NODES + i];
    deg[i] = s;
}

// single block: exclusive scan deg -> indptr (R5-proven pattern, 20 loads/thread)
__global__ __launch_bounds__(1024) void scan1b_kernel(const int* __restrict__ deg,
                                                      int* __restrict__ indptr) {
    const int T = 1024;
    const int C = (N_NODES + T - 1) / T;   // 20 per thread
    __shared__ int sums[T];
    int t = threadIdx.x;
    int base = t * C;
    int local[C];
    int s = 0;
#pragma unroll
    for (int i = 0; i < C; i++) {
        int idx = base + i;
        int v = (idx < N_NODES) ? deg[idx] : 0;
        local[i] = s;
        s += v;
    }
    sums[t] = s;
    __syncthreads();
    for (int off = 1; off < T; off <<= 1) {
        int v = (t >= off) ? sums[t - off] : 0;
        __syncthreads();
        sums[t] += v;
        __syncthreads();
    }
    int prefix = (t == 0) ? 0 : sums[t - 1];
#pragma unroll
    for (int i = 0; i < C; i++) {
        int idx = base + i;
        if (idx < N_NODES) indptr[idx] = prefix + local[i];
    }
    if (t == T - 1) indptr[N_NODES] = prefix + s;   // == E_TOT
}

// grid-parallel: rewrite cnt8[s][i] (counts) into ABSOLUTE scatter cursors
__global__ void cursor_kernel(const int* __restrict__ indptr, int* __restrict__ cnt8) {
    int i = blockIdx.x * blockDim.x + threadIdx.x;
    if (i >= N_NODES) return;
    int running = indptr[i];
#pragma unroll
    for (int s8 = 0; s8 < NSHARD; s8++) {
        int c = cnt8[s8 * N_NODES + i];
        cnt8[s8 * N_NODES + i] = running;
        running += c;
    }
}

// sharded-cursor edge scatter (shard mapping matches count_kernel exactly)
__global__ void scatter_edges_kernel(const int* __restrict__ edge_src,
                                     const int* __restrict__ edge_dst,
                                     int* __restrict__ cnt8,
                                     int* __restrict__ ssrc) {
    int i = blockIdx.x * blockDim.x + threadIdx.x;
    if (i >= E_TOT) return;
    int shard = blockIdx.x & (NSHARD - 1);
    int d, s;
    if (i < N_EDGES) { d = edge_dst[i]; s = edge_src[i]; }
    else             { d = i - N_EDGES; s = d; }
    int pos = atomicAdd(&cnt8[shard * N_NODES + d], 1);   // absolute cursor
    ssrc[pos] = s;
}

// ---------------- fp32 tiled GEMM + bias + optional relu (R3-proven form) ----------------

__global__ __launch_bounds__(256) void gemm_bias_act(const float* __restrict__ A,
                                                     const float* __restrict__ B,
                                                     const float* __restrict__ bias,
                                                     float* __restrict__ C,
                                                     int M, int Nn, int K, int relu) {
    __shared__ float As[16][65];
    __shared__ float Bs[16][65];
    int tid = threadIdx.x;
    int tx = tid & 15, ty = tid >> 4;
    int row0 = blockIdx.x * 64, col0 = blockIdx.y * 64;
    float acc[4][4] = {};
    for (int k0 = 0; k0 < K; k0 += 16) {
        {
            int r_ = tid >> 2;
            int kq = (tid & 3) * 4;
            int gr = row0 + r_;
            float4 a4 = make_float4(0.f, 0.f, 0.f, 0.f);
            if (gr < M) a4 = *(const float4*)&A[(long)gr * K + k0 + kq];
            As[kq + 0][r_] = a4.x; As[kq + 1][r_] = a4.y;
            As[kq + 2][r_] = a4.z; As[kq + 3][r_] = a4.w;
        }
        {
            int kr = tid >> 4;
            int cq = (tid & 15) * 4;
            float4 b4 = *(const float4*)&B[(long)(k0 + kr) * Nn + col0 + cq];
            Bs[kr][cq + 0] = b4.x; Bs[kr][cq + 1] = b4.y;
            Bs[kr][cq + 2] = b4.z; Bs[kr][cq + 3] = b4.w;
        }
        __syncthreads();
#pragma unroll
        for (int kk = 0; kk < 16; kk++) {
            float a[4], b[4];
#pragma unroll
            for (int i = 0; i < 4; i++) a[i] = As[kk][ty * 4 + i];
#pragma unroll
            for (int j = 0; j < 4; j++) b[j] = Bs[kk][tx * 4 + j];
#pragma unroll
            for (int i = 0; i < 4; i++)
#pragma unroll
                for (int j = 0; j < 4; j++) acc[i][j] += a[i] * b[j];
        }
        __syncthreads();
    }
#pragma unroll
    for (int i = 0; i < 4; i++) {
        int gr = row0 + ty * 4 + i;
        if (gr >= M) continue;
#pragma unroll
        for (int j = 0; j < 4; j++) {
            int gc = col0 + tx * 4 + j;
            float v = acc[i][j] + bias[gc];
            if (relu) v = fmaxf(v, 0.f);
            C[(long)gr * Nn + gc] = v;
        }
    }
}

// ---------------- initial normalize: one wave per row, shfl-only ----------------

__global__ __launch_bounds__(256) void normalize0_kernel(const float* __restrict__ h,
                                                         unsigned short* __restrict__ hnb,
                                                         float* __restrict__ r) {
    int wid = threadIdx.x >> 6, lane = threadIdx.x & 63;
    int i = blockIdx.x * 4 + wid;            // grid exact: 5000*4 = 20000
    const float4* h4 = (const float4*)(h + (long)i * HIDDEN);
    float4 v = h4[lane];
    float ss = v.x * v.x + v.y * v.y + v.z * v.z + v.w * v.w;
#pragma unroll
    for (int off = 32; off; off >>= 1) ss += __shfl_xor(ss, off);
    float rr = sqrtf(ss + 1e-12f);
    float ir = 1.f / rr;
    uint2 o;
    o.x = pk2(v.x * ir, v.y * ir);
    o.y = pk2(v.z * ir, v.w * ir);
    ((uint2*)(hnb + (long)i * HIDDEN))[lane] = o;
    if (lane == 0) r[i] = rr;
}

// ---------------- fused AGNN layer ----------------
// ONE node per wave; edge list split across four 16-lane groups (4 streams).
// All 16 lanes of a group share cnt; loop bound = ceil(deg/4) directly (no
// cross-node balancing needed -> degree sort dropped entirely).
// No-max softmax (cosine logits bounded): merge = plain sums, 2 shfl rounds.

__global__ __launch_bounds__(256) void agnn_kernel(const unsigned short* __restrict__ hnb,
                                                   const float* __restrict__ rin,
                                                   const int* __restrict__ indptr,
                                                   const int* __restrict__ ssrc,
                                                   unsigned short* __restrict__ hnout,
                                                   float* __restrict__ rout,
                                                   float* __restrict__ hout,
                                                   int write_hn) {
    int lane = threadIdx.x & 63;
    int wid  = threadIdx.x >> 6;
    int sub  = lane >> 4;          // which quarter of the edge list (0..3)
    int gl   = lane & 15;          // lane in 16-group
    int node = blockIdx.x * 4 + wid;   // grid exact: 5000*4 = 20000

    const uint4* tab4 = (const uint4*)hnb;   // one uint4 = 8 bf16; row = 32 uint4
    long nb = (long)node * 32 + gl * 2;
    uint4 ha = tab4[nb], hb = tab4[nb + 1];
    f32x2 hd2[8];
    hd2[0] = up2(ha.x) * LOG2E; hd2[1] = up2(ha.y) * LOG2E;
    hd2[2] = up2(ha.z) * LOG2E; hd2[3] = up2(ha.w) * LOG2E;
    hd2[4] = up2(hb.x) * LOG2E; hd2[5] = up2(hb.y) * LOG2E;
    hd2[6] = up2(hb.z) * LOG2E; hd2[7] = up2(hb.w) * LOG2E;

    int beg = indptr[node], end = indptr[node + 1];
    int deg = end - beg;               // >= 1 (self loop)
    int qb  = deg >> 2, rem = deg & 3;
    int cnt = qb + (sub < rem ? 1 : 0);
    int eb  = beg + sub * qb + min(sub, rem);
    int lim = (cnt > 0) ? (eb + cnt - 1) : beg;   // valid clamp target
    int nmax = qb + (rem ? 1 : 0);     // uniform wave loop bound, no shfl needed

    f32x2 acc[8];
#pragma unroll
    for (int p = 0; p < 8; p++) acc[p] = (f32x2)0.f;
    float z = 0.f;

    // 3-deep pipeline prologue: rows for e0,e1 in flight; index for e2 in flight
    int s0 = ssrc[(0 < cnt) ? eb : lim];
    int s1 = ssrc[min(eb + 1, lim)];
    long b0 = (long)s0 * 32 + gl * 2;
    uint4 v0a = tab4[b0], v0b = tab4[b0 + 1];
    float r0 = rin[s0];
    long b1 = (long)s1 * 32 + gl * 2;
    uint4 v1a = tab4[b1], v1b = tab4[b1 + 1];
    float r1 = rin[s1];
    int s2 = ssrc[min(eb + 2, lim)];

    for (int i = 0; i < nmax; i++) {
        uint4 ca = v0a, cb = v0b;
        float cr = r0;
        v0a = v1a; v0b = v1b; r0 = r1;
        long b2 = (long)s2 * 32 + gl * 2;
        v1a = tab4[b2]; v1b = tab4[b2 + 1];
        r1 = rin[s2];
        s2 = ssrc[min(eb + i + 3, lim)];

        f32x2 cf[8];
        cf[0] = up2(ca.x); cf[1] = up2(ca.y); cf[2] = up2(ca.z); cf[3] = up2(ca.w);
        cf[4] = up2(cb.x); cf[5] = up2(cb.y); cf[6] = up2(cb.z); cf[7] = up2(cb.w);
        f32x2 da = cf[0] * hd2[0];
        f32x2 db = cf[1] * hd2[1];
        da += cf[2] * hd2[2];  db += cf[3] * hd2[3];
        da += cf[4] * hd2[4];  db += cf[5] * hd2[5];
        da += cf[6] * hd2[6];  db += cf[7] * hd2[7];
        f32x2 d2 = da + db;
        float d = d2.x + d2.y;
        d += __shfl_xor(d, 1);
        d += __shfl_xor(d, 2);
        d += __shfl_xor(d, 4);
        d += __shfl_xor(d, 8);
        float w = (i < cnt) ? exp2f(d) : 0.f;   // mask tail of shorter streams
        z += w;
        float wr = w * cr;
#pragma unroll
        for (int p = 0; p < 8; p++) acc[p] += cf[p] * wr;
    }

    // merge the 4 partial streams (plain sums -- no max state)
    z += __shfl_xor(z, 16);
    z += __shfl_xor(z, 32);
#pragma unroll
    for (int p = 0; p < 8; p++) {
        acc[p].x += __shfl_xor(acc[p].x, 16);
        acc[p].y += __shfl_xor(acc[p].y, 16);
        acc[p].x += __shfl_xor(acc[p].x, 32);
        acc[p].y += __shfl_xor(acc[p].y, 32);
    }

    float inv = 1.f / z;
    f32x2 o[8];
#pragma unroll
    for (int p = 0; p < 8; p++) {
        f32x2 t = acc[p] * inv;
        t.x = fmaxf(t.x, 0.f);
        t.y = fmaxf(t.y, 0.f);
        o[p] = t;
    }

    if (write_hn) {
        float ss = 0.f;
#pragma unroll
        for (int p = 0; p < 8; p++) ss += o[p].x * o[p].x + o[p].y * o[p].y;
        ss += __shfl_xor(ss, 1);
        ss += __shfl_xor(ss, 2);
        ss += __shfl_xor(ss, 4);
        ss += __shfl_xor(ss, 8);     // full row lives in each 16-lane group
        float rr = sqrtf(ss + 1e-12f);
        float ir = 1.f / rr;
        if (sub == 0) {
            uint4 oa, ob;
            oa.x = pk2(o[0].x * ir, o[0].y * ir);
            oa.y = pk2(o[1].x * ir, o[1].y * ir);
            oa.z = pk2(o[2].x * ir, o[2].y * ir);
            oa.w = pk2(o[3].x * ir, o[3].y * ir);
            ob.x = pk2(o[4].x * ir, o[4].y * ir);
            ob.y = pk2(o[5].x * ir, o[5].y * ir);
            ob.z = pk2(o[6].x * ir, o[6].y * ir);
            ob.w = pk2(o[7].x * ir, o[7].y * ir);
            uint4* outt = (uint4*)hnout;
            outt[nb] = oa;
            outt[nb + 1] = ob;
            if (gl == 0) rout[node] = rr;
        }
    } else {
        if (sub == 0) {
            float4* ho = (float4*)(hout + (long)node * HIDDEN + gl * 16);
            ho[0] = make_float4(o[0].x, o[0].y, o[1].x, o[1].y);
            ho[1] = make_float4(o[2].x, o[2].y, o[3].x, o[3].y);
            ho[2] = make_float4(o[4].x, o[4].y, o[5].x, o[5].y);
            ho[3] = make_float4(o[6].x, o[6].y, o[7].x, o[7].y);
        }
    }
}

// ---------------- launch (13 kernels) ----------------

extern "C" void kernel_launch(void* const* d_in, const int* in_sizes, int n_in,
                              void* d_out, int out_size, void* d_ws, size_t ws_size,
                              hipStream_t stream) {
    const float* x  = (const float*)d_in[0];
    const int* esrc = (const int*)d_in[1];
    const int* edst = (const int*)d_in[2];
    const float* W1 = (const float*)d_in[3];
    const float* b1 = (const float*)d_in[4];
    const float* W2 = (const float*)d_in[5];
    const float* b2 = (const float*)d_in[6];
    float* out = (float*)d_out;

    char* ws = (char*)d_ws;
    float*          h0     = (float*)(ws);                          // 20,480,000 B
    unsigned short* hnA    = (unsigned short*)(ws + 20480000);      // 10,240,000 B
    unsigned short* hnB    = (unsigned short*)(ws + 30720000);      // 10,240,000 B
    float*          rA     = (float*)(ws + 40960000);               // 80,000 B
    float*          rB     = (float*)(ws + 41040000);               // 80,000 B
    int*            indptr = (int*)  (ws + 41120000);               // 80,004 B (pad)
    int*            cnt8   = (int*)  (ws + 41200256);               // 640,000 B
    int*            ssrc   = (int*)  (ws + 41840256);               // 2,640,000 B
    int*            deg    = (int*)  (ws + 44480256);               // 80,000 B

    zero_cnt8_kernel<<<(NSHARD * N_NODES + 255) / 256, 256, 0, stream>>>(cnt8);
    count_kernel<<<(E_TOT + 255) / 256, 256, 0, stream>>>(edst, cnt8);
    sumdeg_kernel<<<(N_NODES + 255) / 256, 256, 0, stream>>>(cnt8, deg);
    scan1b_kernel<<<1, 1024, 0, stream>>>(deg, indptr);
    cursor_kernel<<<(N_NODES + 255) / 256, 256, 0, stream>>>(indptr, cnt8);
    scatter_edges_kernel<<<(E_TOT + 255) / 256, 256, 0, stream>>>(esrc, edst, cnt8, ssrc);

    dim3 g1((N_NODES + 63) / 64, HIDDEN / 64);
    gemm_bias_act<<<g1, 256, 0, stream>>>(x, W1, b1, h0, N_NODES, HIDDEN, IN_DIM, 1);

    normalize0_kernel<<<N_NODES / 4, 256, 0, stream>>>(h0, hnA, rA);

    int nblk = N_NODES / 4;   // 5000, exact
    // L0: A -> B, L1: B -> A, L2: A -> B, L3: B -> h0 (fp32)
    agnn_kernel<<<nblk, 256, 0, stream>>>(hnA, rA, indptr, ssrc, hnB, rB, h0, 1);
    agnn_kernel<<<nblk, 256, 0, stream>>>(hnB, rB, indptr, ssrc, hnA, rA, h0, 1);
    agnn_kernel<<<nblk, 256, 0, stream>>>(hnA, rA, indptr, ssrc, hnB, rB, h0, 1);
    agnn_kernel<<<nblk, 256, 0, stream>>>(hnB, rB, indptr, ssrc, hnA, rA, h0, 0);

    dim3 g2((N_NODES + 63) / 64, OUT_DIM / 64);
    gemm_bias_act<<<g2, 256, 0, stream>>>(h0, W2, b2, out, N_NODES, OUT_DIM, HIDDEN, 0);
}